// Round 6
// baseline (12017.542 us; speedup 1.0000x reference)
//
#include <hip/hip_runtime.h>
#include <hip/hip_fp16.h>

#define N_ 256
#define C_ 3
#define T_ 300
#define V_ 25
#define H_ 256
#define G4_ 1024   // 4*H
#define IN_ 75
#define XP1_ 96    // padded input-K
#define NCLS_ 60

typedef _Float16 half_t;
typedef __attribute__((ext_vector_type(8))) _Float16 half8;
typedef __attribute__((ext_vector_type(4))) float f32x4;
typedef __attribute__((ext_vector_type(4))) unsigned int uint4v;
typedef __attribute__((ext_vector_type(2))) unsigned int uint2v;

static_assert(sizeof(half8) == 16, "half8 must be 16B");

__device__ __forceinline__ float tanh_f(float x) {
  x = fminf(fmaxf(x, -15.0f), 15.0f);
  float e = __expf(2.0f * x);
  return (e - 1.0f) / (e + 1.0f);
}

// ---- coherent (IF-level) ops: bypass non-coherent L1/L2 ----
__device__ __forceinline__ half8 gload16_cc(const void* p) {
  uint4v r;
  asm volatile("global_load_dwordx4 %0, %1, off sc0 sc1" : "=v"(r) : "v"(p));
  return __builtin_bit_cast(half8, r);
}
__device__ __forceinline__ void store8_cc(void* p, uint2v v) {
  asm volatile("global_store_dwordx2 %0, %1, off sc0 sc1" :: "v"(p), "v"(v) : "memory");
}
__device__ __forceinline__ void waitvm0() {
  asm volatile("s_waitcnt vmcnt(0)" ::: "memory");
  __builtin_amdgcn_sched_barrier(0);
}

// ---------- pack [Whh | Wih | 0pad] rows into fp16, bias = bih+bhh ----------
__global__ void pack_wcat(const float* __restrict__ Whh, const float* __restrict__ Wih,
                          const float* __restrict__ bih, const float* __restrict__ bhh,
                          half_t* __restrict__ dstW, float* __restrict__ dstB,
                          int inDim, int Kc) {
  int idx = blockIdx.x * 256 + threadIdx.x;
  int tot = G4_ * Kc;
  if (idx < tot) {
    int row = idx / Kc, k = idx % Kc;
    float v = 0.0f;
    if (k < H_) v = Whh[row * H_ + k];
    else if (k - H_ < inDim) v = Wih[row * inDim + (k - H_)];
    dstW[idx] = (half_t)v;
  }
  if (idx < G4_) dstB[idx] = bih[idx] + bhh[idx];
}

// ---------- pack x -> seqb[p][n][t][96] fp16 ----------
__global__ void pack_seq(const float* __restrict__ x, half_t* __restrict__ seqb) {
  int idx = blockIdx.x * 256 + threadIdx.x;
  const int tot = 2 * N_ * T_ * XP1_;
  if (idx >= tot) return;
  int k = idx % XP1_; int r = idx / XP1_;
  int t = r % T_; int r2 = r / T_;
  int n = r2 % N_; int p = r2 / N_;
  float v = 0.0f;
  if (k < IN_) {
    int c = k / V_, vv = k % V_;
    v = x[(((size_t)n * C_ + c) * T_ + t) * (V_ * 2) + vv * 2 + p];
  }
  seqb[idx] = (half_t)v;
}

// ---------- cooperative LSTM, sentinel data-poll (no flags) ----------
// group g = 32 sample rows; 8 members (32-unit slices); member m of group g is
// block m*NGROUPS+g. Weights in VGPRs. h exchanged via depth-3 coherent ring
// [slot][member][rr rows][32]; consumers poll data for sentinel 0xFFFF halves.
// Invariant: member at step t sentinels slot (t+1)%3 AFTER its poll, drains
// before publishing h_t -> pollers of h_{t+1} can never see stale data.
template<int KT, int NGROUPS>
__global__ __launch_bounds__(256, 1) void lstm_sent(
    const half_t* __restrict__ W0, const half_t* __restrict__ W1,
    const float* __restrict__ b0, const float* __restrict__ b1,
    const half_t* __restrict__ xseq, int XK,
    half_t* __restrict__ ring, int rr,
    half_t* __restrict__ hseq,
    float* __restrict__ hlast0, float* __restrict__ hlast1) {
  constexpr int XKT = KT - 8;
  constexpr int Kc = KT * 32;
  const int member = blockIdx.x / NGROUPS;
  const int g = blockIdx.x % NGROUPS;
  const int run = (NGROUPS == 32) ? (g >> 4) : 0;
  const int ringRow0 = g * 32;
  const int seqRow0 = ringRow0 - run * 512;
  const int u0 = member * 32;

  const half_t* __restrict__ Wcat = run ? W1 : W0;
  const float* __restrict__ bias = run ? b1 : b0;
  float* hlast = run ? hlast1 : hlast0;

  const int tid = threadIdx.x, lane = tid & 63, wave = tid >> 6;
  const int col = lane & 15, khalf = lane >> 4, klo8 = khalf * 8, gq = col & 3;
  const int srow = tid >> 3, spart = tid & 7;  // store mapping: 32 rows x 8 parts

  __shared__ __align__(16) half_t axh[2 * 8 * 16 * 32];  // broadcast A panel (16 KB)
  __shared__ __align__(8)  half_t hstage[32 * 32];       // output slice staging

  // ---- weights + bias -> registers ----
  half8 wreg[2][KT];
  float brg[2];
#pragma unroll
  for (int ntp = 0; ntp < 2; ++ntp) {
    int lrow = (wave * 2 + ntp) * 16 + col;
    int grow = (lrow & 3) * 256 + u0 + (lrow >> 2);
#pragma unroll
    for (int kt = 0; kt < KT; ++kt)
      wreg[ntp][kt] = *reinterpret_cast<const half8*>(Wcat + (size_t)grow * Kc + kt * 32 + klo8);
    brg[ntp] = bias[grow];
  }

  const half_t* xrow[2];
#pragma unroll
  for (int c = 0; c < 2; ++c)
    xrow[c] = xseq + (size_t)(seqRow0 + c * 16 + col) * T_ * XK + klo8;

  float creg[2][2][4] = {};

#pragma unroll 1
  for (int t = 0; t < T_; ++t) {
    const int sc_ = t % 3;
    const int sp_ = (t + 2) % 3;
    const int sn_ = (t + 1) % 3;

    // ---- x fragments (normal cached loads, overlap with poll) ----
    half8 ax[2][XKT];
#pragma unroll
    for (int c = 0; c < 2; ++c)
#pragma unroll
      for (int kx = 0; kx < XKT; ++kx)
        ax[c][kx] = *reinterpret_cast<const half8*>(xrow[c] + (size_t)t * XK + kx * 32);

    const bool hasH = (t > 0);
    half8 ah[2][8];
    if (hasH) {
      if (wave == 0) {
        int guard = 0;
        for (;;) {
#pragma unroll
          for (int c = 0; c < 2; ++c)
#pragma unroll
            for (int kt = 0; kt < 8; ++kt)
              ah[c][kt] = gload16_cc(
                  ring + ((size_t)(sp_ * 8 + kt) * rr + ringRow0 + c * 16 + col) * 32 + klo8);
          waitvm0();
          unsigned bad = 0;
#pragma unroll
          for (int c = 0; c < 2; ++c)
#pragma unroll
            for (int kt = 0; kt < 8; ++kt) {
              uint4v u = __builtin_bit_cast(uint4v, ah[c][kt]);
              bad |= ((u[0] & 0xFFFFu) == 0xFFFFu) | ((u[1] & 0xFFFFu) == 0xFFFFu) |
                     ((u[2] & 0xFFFFu) == 0xFFFFu) | ((u[3] & 0xFFFFu) == 0xFFFFu);
            }
          if (__all(bad == 0u)) break;
          if (++guard > (1 << 17)) break;  // safety net
          __builtin_amdgcn_s_sleep(1);
        }
        // broadcast full A panel through LDS (conflict-free b128)
#pragma unroll
        for (int c = 0; c < 2; ++c)
#pragma unroll
          for (int kt = 0; kt < 8; ++kt)
            *reinterpret_cast<half8*>(&axh[((c * 8 + kt) * 16 + col) * 32 + klo8]) = ah[c][kt];
      }
      __syncthreads();
      __builtin_amdgcn_sched_barrier(0);
#pragma unroll
      for (int c = 0; c < 2; ++c)
#pragma unroll
        for (int kt = 0; kt < 8; ++kt)
          ah[c][kt] = *reinterpret_cast<const half8*>(&axh[((c * 8 + kt) * 16 + col) * 32 + klo8]);
    }

    // ---- sentinel own region of NEXT slot (post-poll; drains before publish) ----
    {
      uint2v sent = {0xFFFFFFFFu, 0xFFFFFFFFu};
      store8_cc(ring + ((size_t)(sn_ * 8 + member) * rr + ringRow0 + srow) * 32 + spart * 4, sent);
    }

    // ---- MFMA + activations for both 16-row chunks ----
#pragma unroll
    for (int c = 0; c < 2; ++c) {
      f32x4 acc[2];
      acc[0] = (f32x4){brg[0], brg[0], brg[0], brg[0]};
      acc[1] = (f32x4){brg[1], brg[1], brg[1], brg[1]};
      if (hasH) {
#pragma unroll
        for (int kt = 0; kt < 8; ++kt) {
          acc[0] = __builtin_amdgcn_mfma_f32_16x16x32_f16(ah[c][kt], wreg[0][kt], acc[0], 0, 0, 0);
          acc[1] = __builtin_amdgcn_mfma_f32_16x16x32_f16(ah[c][kt], wreg[1][kt], acc[1], 0, 0, 0);
        }
      }
#pragma unroll
      for (int kx = 0; kx < XKT; ++kx) {
        acc[0] = __builtin_amdgcn_mfma_f32_16x16x32_f16(ax[c][kx], wreg[0][8 + kx], acc[0], 0, 0, 0);
        acc[1] = __builtin_amdgcn_mfma_f32_16x16x32_f16(ax[c][kx], wreg[1][8 + kx], acc[1], 0, 0, 0);
      }
#pragma unroll
      for (int ntp = 0; ntp < 2; ++ntp) {
        int nt = wave * 2 + ntp;
        int ul = nt * 4 + (col >> 2);
#pragma unroll
        for (int r = 0; r < 4; ++r) {
          float v = acc[ntp][r];
          float y = (gq == 2) ? 2.0f * v : v;
          float s = 1.0f / (1.0f + __expf(-y));
          float av = (gq == 2) ? (2.0f * s - 1.0f) : s;
          float b1v = __shfl_xor(av, 1);
          float b2v = __shfl_xor(av, 2);
          float b3v = __shfl_xor(b1v, 2);
          auto pick = [&](int k2) { return k2 == 0 ? av : (k2 == 1 ? b1v : (k2 == 2 ? b2v : b3v)); };
          float iv = pick(gq), fv = pick(gq ^ 1), gv = pick(gq ^ 2), ov = pick(gq ^ 3);
          float cc = fv * creg[c][ntp][r] + iv * gv;
          creg[c][ntp][r] = cc;
          float h = ov * tanh_f(cc);
          if (gq == 0) {
            int s_ = c * 16 + khalf * 4 + r;
            hstage[s_ * 32 + ul] = (half_t)h;
            if (hlast != nullptr && t == T_ - 1)
              hlast[(size_t)(seqRow0 + s_) * H_ + u0 + ul] = h;
          }
        }
      }
    }
    __syncthreads();

    // ---- drain sentinels, then publish h (no post-store drain needed) ----
    waitvm0();
    {
      uint2v val = *reinterpret_cast<const uint2v*>(&hstage[srow * 32 + spart * 4]);
      store8_cc(ring + ((size_t)(sc_ * 8 + member) * rr + ringRow0 + srow) * 32 + spart * 4, val);
      if (hseq)
        *reinterpret_cast<uint2v*>(
            &hseq[((size_t)(seqRow0 + srow) * T_ + t) * H_ + u0 + spart * 4]) = val;
    }
  }
}

// ---------- angles/trans FC + rotation matrices ----------
__global__ void fc3_rot(const float* __restrict__ hrot, const float* __restrict__ htr,
                        const float* __restrict__ rfcW, const float* __restrict__ rfcb,
                        const float* __restrict__ tfcW, const float* __restrict__ tfcb,
                        float* __restrict__ rt) {
  int idx = blockIdx.x * blockDim.x + threadIdx.x;
  if (idx >= 2 * N_) return;
  const float* h1 = hrot + (size_t)idx * H_;
  const float* h2 = htr + (size_t)idx * H_;
  float ang[3], tr[3];
#pragma unroll
  for (int i = 0; i < 3; ++i) {
    float a = rfcb[i], b = tfcb[i];
    for (int j = 0; j < H_; ++j) { a += h1[j] * rfcW[i * H_ + j]; b += h2[j] * tfcW[i * H_ + j]; }
    ang[i] = a * 3.14159265358979323846f;
    tr[i] = b;
  }
  float c0 = cosf(ang[0]), s0 = sinf(ang[0]);
  float c1 = cosf(ang[1]), s1 = sinf(ang[1]);
  float c2 = cosf(ang[2]), s2 = sinf(ang[2]);
  float Rx[3][3] = {{1, 0, 0}, {0, c0, s0}, {0, -s0, c0}};
  float Ry[3][3] = {{c1, 0, -s1}, {0, 1, 0}, {s1, 0, c1}};
  float Rz[3][3] = {{c2, s2, 0}, {-s2, c2, 0}, {0, 0, 1}};
  float A[3][3], R[3][3];
  for (int i = 0; i < 3; ++i)
    for (int j = 0; j < 3; ++j) {
      float s = 0;
      for (int k = 0; k < 3; ++k) s += Rx[i][k] * Ry[k][j];
      A[i][j] = s;
    }
  for (int i = 0; i < 3; ++i)
    for (int j = 0; j < 3; ++j) {
      float s = 0;
      for (int k = 0; k < 3; ++k) s += A[i][k] * Rz[k][j];
      R[i][j] = s;
    }
  float* o = rt + (size_t)idx * 12;
  for (int i = 0; i < 9; ++i) o[i] = R[i / 3][i % 3];
  for (int i = 0; i < 3; ++i) o[9 + i] = tr[i];
}

// ---------- seq2 = R @ (x - trans), overwrites seqb ----------
__global__ void transform_seq(const float* __restrict__ x, const float* __restrict__ rt,
                              half_t* __restrict__ seqb) {
  int idx = blockIdx.x * 256 + threadIdx.x;
  const int tot = 2 * N_ * T_ * V_;
  if (idx >= tot) return;
  int v = idx % V_; int r = idx / V_;
  int t = r % T_; int r2 = r / T_;
  int n = r2 % N_; int p = r2 / N_;
  const float* o = rt + ((size_t)p * N_ + n) * 12;
  float xv[3];
#pragma unroll
  for (int c = 0; c < 3; ++c)
    xv[c] = x[(((size_t)n * C_ + c) * T_ + t) * (V_ * 2) + v * 2 + p] - o[9 + c];
  size_t base = (((size_t)p * N_ + n) * T_ + t) * XP1_;
#pragma unroll
  for (int i = 0; i < 3; ++i) {
    float s = o[i * 3 + 0] * xv[0] + o[i * 3 + 1] * xv[1] + o[i * 3 + 2] * xv[2];
    seqb[base + i * V_ + v] = (half_t)s;
  }
}

// ---------- maxpool over persons + final FC ----------
__global__ void final_fc(const float* __restrict__ hM2, const float* __restrict__ fcW,
                         const float* __restrict__ fcb, float* __restrict__ out) {
  int n = blockIdx.x;
  __shared__ float hm[H_];
  for (int j = threadIdx.x; j < H_; j += blockDim.x)
    hm[j] = fmaxf(hM2[(size_t)n * H_ + j], hM2[(size_t)(N_ + n) * H_ + j]);
  __syncthreads();
  if (threadIdx.x < NCLS_) {
    float acc = fcb[threadIdx.x];
    for (int j = 0; j < H_; ++j) acc += hm[j] * fcW[threadIdx.x * H_ + j];
    out[n * NCLS_ + threadIdx.x] = acc;
  }
}

extern "C" void kernel_launch(void* const* d_in, const int* in_sizes, int n_in,
                              void* d_out, int out_size, void* d_ws, size_t ws_size,
                              hipStream_t stream) {
  const float* x       = (const float*)d_in[0];
  const float* rot_Wih = (const float*)d_in[1];
  const float* rot_Whh = (const float*)d_in[2];
  const float* rot_bih = (const float*)d_in[3];
  const float* rot_bhh = (const float*)d_in[4];
  const float* rot_fcW = (const float*)d_in[5];
  const float* rot_fcb = (const float*)d_in[6];
  const float* tr_Wih  = (const float*)d_in[7];
  const float* tr_Whh  = (const float*)d_in[8];
  const float* tr_bih  = (const float*)d_in[9];
  const float* tr_bhh  = (const float*)d_in[10];
  const float* tr_fcW  = (const float*)d_in[11];
  const float* tr_fcb  = (const float*)d_in[12];
  const float* m0_Wih  = (const float*)d_in[13];
  const float* m0_Whh  = (const float*)d_in[14];
  const float* m0_bih  = (const float*)d_in[15];
  const float* m0_bhh  = (const float*)d_in[16];
  const float* m1_Wih  = (const float*)d_in[17];
  const float* m1_Whh  = (const float*)d_in[18];
  const float* m1_bih  = (const float*)d_in[19];
  const float* m1_bhh  = (const float*)d_in[20];
  const float* m2_Wih  = (const float*)d_in[21];
  const float* m2_Whh  = (const float*)d_in[22];
  const float* m2_bih  = (const float*)d_in[23];
  const float* m2_bhh  = (const float*)d_in[24];
  const float* fcW     = (const float*)d_in[25];
  const float* fcb     = (const float*)d_in[26];

  char* ws = (char*)d_ws;
  size_t off = 0;
  auto take = [&](size_t b) -> void* {
    void* pp = ws + off;
    off = (off + b + 255) & ~(size_t)255;
    return pp;
  };
  half_t* WC_ROT = (half_t*)take((size_t)G4_ * 352 * 2);
  half_t* WC_TR  = (half_t*)take((size_t)G4_ * 352 * 2);
  half_t* WC_M0  = (half_t*)take((size_t)G4_ * 352 * 2);
  half_t* WC_M1  = (half_t*)take((size_t)G4_ * 512 * 2);
  half_t* WC_M2  = (half_t*)take((size_t)G4_ * 512 * 2);
  float* B_ROT = (float*)take((size_t)G4_ * 4);
  float* B_TR  = (float*)take((size_t)G4_ * 4);
  float* B_M0  = (float*)take((size_t)G4_ * 4);
  float* B_M1  = (float*)take((size_t)G4_ * 4);
  float* B_M2  = (float*)take((size_t)G4_ * 4);
  half_t* SEQB = (half_t*)take((size_t)2 * N_ * T_ * XP1_ * 2);
  float* HL_ROT = (float*)take((size_t)2 * N_ * H_ * 4);
  float* HL_TR  = (float*)take((size_t)2 * N_ * H_ * 4);
  float* HL_M2  = (float*)take((size_t)2 * N_ * H_ * 4);
  float* RT     = (float*)take((size_t)2 * N_ * 12 * 4);
  half_t* RINGP  = (half_t*)take((size_t)3 * 8 * 1024 * 32 * 2);
  half_t* RINGM0 = (half_t*)take((size_t)3 * 8 * 512 * 32 * 2);
  half_t* RINGM1 = (half_t*)take((size_t)3 * 8 * 512 * 32 * 2);
  half_t* RINGM2 = (half_t*)take((size_t)3 * 8 * 512 * 32 * 2);
  half_t* HS0 = (half_t*)take((size_t)2 * N_ * T_ * H_ * 2);
  half_t* HS1 = (half_t*)take((size_t)2 * N_ * T_ * H_ * 2);

  // pre-sentinel all rings (0xFF bytes == fp16 0xFFFF halves)
  hipMemsetAsync(RINGP, 0xFF, (size_t)3 * 8 * 1024 * 32 * 2, stream);
  hipMemsetAsync(RINGM0, 0xFF, (size_t)3 * 8 * 512 * 32 * 2, stream);
  hipMemsetAsync(RINGM1, 0xFF, (size_t)3 * 8 * 512 * 32 * 2, stream);
  hipMemsetAsync(RINGM2, 0xFF, (size_t)3 * 8 * 512 * 32 * 2, stream);

  // ---- pack weights (fp16) + fused biases ----
  pack_wcat<<<1408, 256, 0, stream>>>(rot_Whh, rot_Wih, rot_bih, rot_bhh, WC_ROT, B_ROT, IN_, 352);
  pack_wcat<<<1408, 256, 0, stream>>>(tr_Whh, tr_Wih, tr_bih, tr_bhh, WC_TR, B_TR, IN_, 352);
  pack_wcat<<<1408, 256, 0, stream>>>(m0_Whh, m0_Wih, m0_bih, m0_bhh, WC_M0, B_M0, IN_, 352);
  pack_wcat<<<2048, 256, 0, stream>>>(m1_Whh, m1_Wih, m1_bih, m1_bhh, WC_M1, B_M1, H_, 512);
  pack_wcat<<<2048, 256, 0, stream>>>(m2_Whh, m2_Wih, m2_bih, m2_bhh, WC_M2, B_M2, H_, 512);

  pack_seq<<<(2 * N_ * T_ * XP1_ + 255) / 256, 256, 0, stream>>>(x, SEQB);

  // ---- phase 1: rot (run0) & tr (run1): 32 groups x 8 members ----
  lstm_sent<11, 32><<<256, 256, 0, stream>>>(
      WC_ROT, WC_TR, B_ROT, B_TR, SEQB, XP1_,
      RINGP, 1024, nullptr, HL_ROT, HL_TR);

  fc3_rot<<<2, 256, 0, stream>>>(HL_ROT, HL_TR, rot_fcW, rot_fcb, tr_fcW, tr_fcb, RT);
  transform_seq<<<(2 * N_ * T_ * V_ + 255) / 256, 256, 0, stream>>>(x, RT, SEQB);

  // ---- stacked main LSTMs (16 groups x 8 members = 128 WGs each) ----
  lstm_sent<11, 16><<<128, 256, 0, stream>>>(
      WC_M0, WC_M0, B_M0, B_M0, SEQB, XP1_,
      RINGM0, 512, HS0, nullptr, nullptr);
  lstm_sent<16, 16><<<128, 256, 0, stream>>>(
      WC_M1, WC_M1, B_M1, B_M1, HS0, H_,
      RINGM1, 512, HS1, nullptr, nullptr);
  lstm_sent<16, 16><<<128, 256, 0, stream>>>(
      WC_M2, WC_M2, B_M2, B_M2, HS1, H_,
      RINGM2, 512, nullptr, HL_M2, HL_M2);

  final_fc<<<256, 64, 0, stream>>>(HL_M2, fcW, fcb, (float*)d_out);
}